// Round 11
// baseline (345.153 us; speedup 1.0000x reference)
//
#include <hip/hip_runtime.h>
#include <math.h>

#define N_NODES 20000
#define N_EDGES 320000
#define DD 128
#define ND (N_NODES * DD)   // 2,560,000
#define ND4 (ND / 4)        // 640,000
#define NPG 2500            // nodes per graph (8 graphs == 8 XCDs)

// red layout: counter k, replica rep (8 replicas, blockIdx&7) at float offset
// (k*8+rep)*16 -> 64B line per (k,rep): no same-line atomic pileup.
#define RED_FLOATS (14 * 8 * 16)   // 1792 floats per set, 2 sets

// ---------------- CSR build ----------------
// Single-block kernel: zero + count (cnt in LDS, 80KB) + scan + red-zeroing.
// Replaces memset + count + scan dispatches (gaps ~0 but kernel time saved:
// 320K LDS atomics ~ a few us vs global-atomic count + separate memset/scan).

__global__ __launch_bounds__(1024) void csr_build_kernel(const int* __restrict__ rows,
                                                         int* __restrict__ row_start,
                                                         int* __restrict__ cursor,
                                                         float* __restrict__ redz) {
    __shared__ int cnt[N_NODES];       // 80000 B
    __shared__ int part[1024];
    const int t = threadIdx.x;

    for (int i = t; i < 2 * RED_FLOATS; i += 1024) redz[i] = 0.0f;
    for (int i = t; i < N_NODES; i += 1024) cnt[i] = 0;
    __syncthreads();

    for (int e = t; e < N_EDGES; e += 1024) atomicAdd(&cnt[rows[e]], 1);
    __syncthreads();

    const int CH = (N_NODES + 1023) / 1024;  // 20
    int lo = t * CH, hi = min(lo + CH, N_NODES);
    int s = 0;
    for (int i = lo; i < hi; ++i) s += cnt[i];
    part[t] = s;
    __syncthreads();
    for (int off = 1; off < 1024; off <<= 1) {
        int v = (t >= off) ? part[t - off] : 0;
        __syncthreads();
        if (t >= off) part[t] += v;
        __syncthreads();
    }
    int run = (t > 0) ? part[t - 1] : 0;
    for (int i = lo; i < hi; ++i) {
        row_start[i] = run;
        cursor[i] = run;
        run += cnt[i];
    }
    if (t == 1023) row_start[N_NODES] = part[1023];
}

__global__ void scatter_kernel(const int* __restrict__ rows, const int* __restrict__ cols,
                               const float* __restrict__ vals, int* __restrict__ cursor,
                               float2* __restrict__ epack) {
    int e = blockIdx.x * blockDim.x + threadIdx.x;
    if (e >= N_EDGES) return;
    int r = rows[e];
    int p = atomicAdd(&cursor[r], 1);
    epack[p] = make_float2(vals[e], __int_as_float(cols[e]));
}

// ---------------- f(z) = LayerNorm(K*z + A z) [+ fused Anderson reduce] ------
// R3-proven structure: 5000 blocks x 128 threads, half-wave per row, float4
// per lane, shfl-broadcast edges, XCD swizzle (b&7 == graph).
// RED=1 (t=6) / RED=2 (t=7): fused H-reduction. zlast == feval input z (zv in
// reg) and F_t == ov (in reg) in BOTH iterations, so only 4/5 extra float4
// loads per thread; block-level butterfly + 8-replica atomics.

struct Slots5 { const float* s[5]; };

__device__ __forceinline__ float dot4(float4 a, float4 b) {
    return a.x * b.x + a.y * b.y + a.z * b.z + a.w * b.w;
}
__device__ __forceinline__ float4 sub4(float4 a, float4 b) {
    return make_float4(a.x - b.x, a.y - b.y, a.z - b.z, a.w - b.w);
}

template <int RED>
__global__ __launch_bounds__(128) void feval_kernel(const float* __restrict__ z,
                                                    const float* __restrict__ Kd,
                                                    const float* __restrict__ lnw,
                                                    const float* __restrict__ lnb,
                                                    const int* __restrict__ row_start,
                                                    const float2* __restrict__ epack,
                                                    float* __restrict__ out,
                                                    Slots5 sl,
                                                    float* __restrict__ red) {
    int b = blockIdx.x;
    int g = b & 7;                 // XCD id == graph id (round-robin dispatch)
    int j = b >> 3;                // 0..624 within graph
    int wv = threadIdx.x >> 6;     // wave in block: 0..1
    int lane = threadIdx.x & 63;
    int l = lane & 31;             // lane within half-wave
    int r = g * NPG + (j << 2) + (wv << 1) + (lane >> 5);
    int d0 = l << 2;               // dims d0..d0+3

    int e0 = row_start[r], e1 = row_start[r + 1];

    float4 zv = *(const float4*)(z + (size_t)r * DD + d0);
    float kd = Kd[r];
    float a0 = kd * zv.x, a1 = kd * zv.y, a2 = kd * zv.z, a3 = kd * zv.w;

    for (int base = e0; base < e1; base += 32) {
        int ew = base + l;
        float2 my_e = (ew < e1) ? epack[ew] : make_float2(0.0f, 0.0f);
        float my_val = my_e.x;
        int my_col = __float_as_int(my_e.y);
        int m = min(32, e1 - base);
        int i = 0;
        for (; i + 4 <= m; i += 4) {
            int c0 = __shfl(my_col, i, 32);
            int c1 = __shfl(my_col, i + 1, 32);
            int c2 = __shfl(my_col, i + 2, 32);
            int c3 = __shfl(my_col, i + 3, 32);
            float v0 = __shfl(my_val, i, 32);
            float v1 = __shfl(my_val, i + 1, 32);
            float v2 = __shfl(my_val, i + 2, 32);
            float v3 = __shfl(my_val, i + 3, 32);
            float4 z0 = *(const float4*)(z + (size_t)c0 * DD + d0);
            float4 z1 = *(const float4*)(z + (size_t)c1 * DD + d0);
            float4 z2 = *(const float4*)(z + (size_t)c2 * DD + d0);
            float4 z3 = *(const float4*)(z + (size_t)c3 * DD + d0);
            a0 = fmaf(v0, z0.x, a0); a1 = fmaf(v0, z0.y, a1); a2 = fmaf(v0, z0.z, a2); a3 = fmaf(v0, z0.w, a3);
            a0 = fmaf(v1, z1.x, a0); a1 = fmaf(v1, z1.y, a1); a2 = fmaf(v1, z1.z, a2); a3 = fmaf(v1, z1.w, a3);
            a0 = fmaf(v2, z2.x, a0); a1 = fmaf(v2, z2.y, a1); a2 = fmaf(v2, z2.z, a2); a3 = fmaf(v2, z2.w, a3);
            a0 = fmaf(v3, z3.x, a0); a1 = fmaf(v3, z3.y, a1); a2 = fmaf(v3, z3.z, a2); a3 = fmaf(v3, z3.w, a3);
        }
        for (; i < m; ++i) {
            int c = __shfl(my_col, i, 32);
            float v = __shfl(my_val, i, 32);
            float4 zc = *(const float4*)(z + (size_t)c * DD + d0);
            a0 = fmaf(v, zc.x, a0); a1 = fmaf(v, zc.y, a1);
            a2 = fmaf(v, zc.z, a2); a3 = fmaf(v, zc.w, a3);
        }
    }

    // half-wave (32-lane) LayerNorm stats over 128 values (4 per lane)
    float s = a0 + a1 + a2 + a3;
    float sq = a0 * a0 + a1 * a1 + a2 * a2 + a3 * a3;
#pragma unroll
    for (int off = 16; off; off >>= 1) {
        s += __shfl_xor(s, off, 64);   // offsets < 32 keep halves separate
        sq += __shfl_xor(sq, off, 64);
    }
    float mu = s * (1.0f / DD);
    float var = sq * (1.0f / DD) - mu * mu;
    float rstd = rsqrtf(var + 1e-5f);

    float4 wv4 = *(const float4*)(lnw + d0);
    float4 bv4 = *(const float4*)(lnb + d0);
    float4 ov;
    ov.x = wv4.x * (a0 - mu) * rstd + bv4.x;
    ov.y = wv4.y * (a1 - mu) * rstd + bv4.y;
    ov.z = wv4.z * (a2 - mu) * rstd + bv4.z;
    ov.w = wv4.w * (a3 - mu) * rstd + bv4.w;
    *(float4*)(out + (size_t)r * DD + d0) = ov;

    if constexpr (RED > 0) {
        // history slots for this element; p[4] = zv when it aliases the input
        float4 p[5];
#pragma unroll
        for (int c = 0; c < 4; ++c) p[c] = *(const float4*)(sl.s[c] + (size_t)r * DD + d0);
        if constexpr (RED == 2) p[4] = *(const float4*)(sl.s[4] + (size_t)r * DD + d0);
        else                    p[4] = zv;
        float4 G[5];
#pragma unroll
        for (int c = 0; c < 4; ++c) G[c] = sub4(p[c + 1], p[c]);
        G[4] = sub4(ov, zv);               // F_t - z_t, both in registers
        float4 dg[4];
#pragma unroll
        for (int a = 0; a < 4; ++a) dg[a] = sub4(G[a + 1], G[a]);

        float acc[14];
        int k = 0;
#pragma unroll
        for (int a = 0; a < 4; ++a)
#pragma unroll
            for (int bb = a; bb < 4; ++bb) { acc[k] = dot4(dg[a], dg[bb]); ++k; }
#pragma unroll
        for (int a = 0; a < 4; ++a) acc[10 + a] = dot4(dg[a], G[4]);

#pragma unroll
        for (int off = 32; off; off >>= 1)
#pragma unroll
            for (int kk = 0; kk < 14; ++kk) acc[kk] += __shfl_xor(acc[kk], off, 64);

        __shared__ float sh[2][14];
        int wv2 = threadIdx.x >> 6, l64 = threadIdx.x & 63;
        if (l64 == 0)
#pragma unroll
            for (int kk = 0; kk < 14; ++kk) sh[wv2][kk] = acc[kk];
        __syncthreads();
        if (threadIdx.x < 14)
            atomicAdd(&red[(threadIdx.x * 8 + (blockIdx.x & 7)) * 16],
                      sh[0][threadIdx.x] + sh[1][threadIdx.x]);
    }
}

// ---------------- Anderson update (solve fused, replicas summed once/block) --

struct Cols5 { const float* f[5]; };

// H = dG^T dG + 0.1 I is SPD -> unpivoted elimination, fully unrolled.
__device__ __forceinline__ float solve_gamma_vals(const float* rl, float* g) {
    float A[4][4], b[4];
    int k = 0;
#pragma unroll
    for (int a = 0; a < 4; ++a)
#pragma unroll
        for (int c = a; c < 4; ++c) { float h = rl[k]; A[a][c] = h; A[c][a] = h; ++k; }
#pragma unroll
    for (int a = 0; a < 4; ++a) A[a][a] += 0.1f;
#pragma unroll
    for (int a = 0; a < 4; ++a) b[a] = rl[10 + a];

#pragma unroll
    for (int col = 0; col < 4; ++col) {
        float inv = 1.0f / A[col][col];
#pragma unroll
        for (int rr = 0; rr < 4; ++rr) {
            if (rr > col) {
                float m = A[rr][col] * inv;
#pragma unroll
                for (int c2 = 0; c2 < 4; ++c2)
                    if (c2 >= col) A[rr][c2] -= m * A[col][c2];
                b[rr] -= m * b[col];
            }
        }
    }
#pragma unroll
    for (int rr = 3; rr >= 0; --rr) {
        float s = b[rr];
#pragma unroll
        for (int c2 = 0; c2 < 4; ++c2)
            if (c2 > rr) s -= A[rr][c2] * g[c2];
        g[rr] = s / A[rr][rr];
    }
    bool fin = isfinite(g[0]) && isfinite(g[1]) && isfinite(g[2]) && isfinite(g[3]);
    return fin ? 1.0f : 0.0f;
}

__global__ __launch_bounds__(256) void update_kernel(Cols5 c, const float* __restrict__ red,
                                                     float* __restrict__ zout) {
    __shared__ float sg[5];
    if (threadIdx.x == 0) {
        float rl[14];
#pragma unroll
        for (int k = 0; k < 14; ++k) {
            float h = 0.f;
#pragma unroll
            for (int rep = 0; rep < 8; ++rep) h += red[(k * 8 + rep) * 16];
            rl[k] = h;
        }
        float gg[4];
        float flag = solve_gamma_vals(rl, gg);
        sg[0] = gg[0]; sg[1] = gg[1]; sg[2] = gg[2]; sg[3] = gg[3]; sg[4] = flag;
    }
    __syncthreads();
    float g0 = sg[0], g1 = sg[1], g2 = sg[2], g3 = sg[3], flag = sg[4];

    int j = blockIdx.x * blockDim.x + threadIdx.x;
    if (j >= ND4) return;
    float4 f0 = ((const float4*)c.f[0])[j];
    float4 f1 = ((const float4*)c.f[1])[j];
    float4 f2 = ((const float4*)c.f[2])[j];
    float4 f3 = ((const float4*)c.f[3])[j];
    float4 f4 = ((const float4*)c.f[4])[j];
    float4 o;
    if (flag != 0.0f) {
        o.x = f4.x - 0.5f * ((f1.x - f0.x) * g0 + (f2.x - f1.x) * g1 + (f3.x - f2.x) * g2 + (f4.x - f3.x) * g3);
        o.y = f4.y - 0.5f * ((f1.y - f0.y) * g0 + (f2.y - f1.y) * g1 + (f3.y - f2.y) * g2 + (f4.y - f3.y) * g3);
        o.z = f4.z - 0.5f * ((f1.z - f0.z) * g0 + (f2.z - f1.z) * g1 + (f3.z - f2.z) * g2 + (f4.z - f3.z) * g3);
        o.w = f4.w - 0.5f * ((f1.w - f0.w) * g0 + (f2.w - f1.w) * g1 + (f3.w - f2.w) * g2 + (f4.w - f3.w) * g3);
    } else {
        o = f4;
    }
    ((float4*)zout)[j] = o;
}

// ---------------- host ----------------

extern "C" void kernel_launch(void* const* d_in, const int* in_sizes, int n_in,
                              void* d_out, int out_size, void* d_ws, size_t ws_size,
                              hipStream_t stream) {
    const float* x_init = (const float*)d_in[0];
    const float* Kd     = (const float*)d_in[1];
    const float* vals   = (const float*)d_in[2];
    const float* lnw    = (const float*)d_in[3];
    const float* lnb    = (const float*)d_in[4];
    const int*   rows   = (const int*)d_in[5];
    const int*   cols   = (const int*)d_in[6];
    float* out = (float*)d_out;

    char* p = (char*)d_ws;
    auto carve = [&](size_t bytes) -> void* {
        void* r = (void*)p;
        p += (bytes + 255) & ~(size_t)255;
        return r;
    };
    float*  Fh        = (float*)carve((size_t)6 * ND * 4);   // rolling f_t history, slot t%6
    float*  red       = (float*)carve(2 * RED_FLOATS * 4);   // 2 sets x 14 ctrs x 8 replicas
    int*    row_start = (int*)carve((N_NODES + 1) * 4);
    int*    cursor    = (int*)carve(N_NODES * 4);
    float2* epack     = (float2*)carve((size_t)N_EDGES * 8);
    float*  zA        = out;  // d_out doubles as storage for Anderson z7

    // CSR build: ONE single-block kernel (cnt in LDS; also zeros red) + scatter
    csr_build_kernel<<<1, 1024, 0, stream>>>(rows, row_start, cursor, red);
    scatter_kernel<<<(N_EDGES + 255) / 256, 256, 0, stream>>>(rows, cols, vals, cursor, epack);

    auto Fslot = [&](int t) -> float* { return Fh + (size_t)(t % 6) * ND; };

    Slots5 sl0 = {};   // unused for RED=0
    for (int t = 0; t < 8; ++t) {
        const float* zsrc = (t == 0) ? x_init : (t <= 6 ? Fslot(t - 1) : zA);

        if (t < 6) {
            feval_kernel<0><<<5000, 128, 0, stream>>>(zsrc, Kd, lnw, lnb, row_start, epack,
                                                      Fslot(t), sl0, (float*)nullptr);
        } else {
            float* redt = red + (t - 6) * RED_FLOATS;
            Slots5 sl;
            if (t == 6) {
                // s6 = F1..F6; s6[4]=F5=zsrc (in-reg zv), s6[5]=F6 (in-reg ov)
                for (int c = 0; c < 4; ++c) sl.s[c] = Fslot(1 + c);
                sl.s[4] = Fslot(5);   // unused (RED=1 uses zv)
                feval_kernel<1><<<5000, 128, 0, stream>>>(zsrc, Kd, lnw, lnb, row_start, epack,
                                                          Fslot(t), sl, redt);
            } else {
                // s6 = F2..F7; load F2..F6, F7 = ov, zlast = zA = zv
                for (int c = 0; c < 5; ++c) sl.s[c] = Fslot(2 + c);
                feval_kernel<2><<<5000, 128, 0, stream>>>(zsrc, Kd, lnw, lnb, row_start, epack,
                                                          Fslot(t), sl, redt);
            }

            Cols5 uc;
            for (int c2 = 0; c2 < 5; ++c2) uc.f[c2] = Fslot(t - 4 + c2);
            float* zdst = (t == 6) ? zA : out;
            update_kernel<<<(ND4 + 255) / 256, 256, 0, stream>>>(uc, redt, zdst);
        }
    }
}

// Round 12
// 286.126 us; speedup vs baseline: 1.2063x; 1.2063x over previous
//
#include <hip/hip_runtime.h>
#include <math.h>

#define N_NODES 20000
#define N_EDGES 320000
#define DD 128
#define ND (N_NODES * DD)   // 2,560,000
#define ND4 (ND / 4)        // 640,000
#define NPG 2500            // nodes per graph (8 graphs == 8 XCDs)

// red layout: counter k, replica rep (8 replicas, blockIdx&7) at float offset
// (k*8+rep)*16 -> 64B line per (k,rep): no same-line atomic pileup.
#define RED_FLOATS (14 * 8 * 16)   // 1792 floats per set, 2 sets

// ---------------- CSR build (R10 scheme: parallel dispatches; R11's fused
// single-block version ran at 0.17% occupancy = 130us. Lesson: fuse only if
// the fused kernel keeps the machine busy.) ----------------

__global__ void count_kernel(const int* __restrict__ rows, int* __restrict__ cnt) {
    int e = blockIdx.x * blockDim.x + threadIdx.x;
    if (e < N_EDGES) atomicAdd(&cnt[rows[e]], 1);
}

__global__ __launch_bounds__(1024) void scan_kernel(const int* __restrict__ cnt,
                                                    int* __restrict__ row_start,
                                                    int* __restrict__ cursor,
                                                    float* __restrict__ redz) {
    const int t = threadIdx.x;
    // zero both replicated red sets (2 x 1792 floats) while we're here
    for (int i = t; i < 2 * RED_FLOATS; i += 1024) redz[i] = 0.0f;
    __shared__ int part[1024];
    const int CH = (N_NODES + 1023) / 1024;  // 20
    int lo = t * CH, hi = min(lo + CH, N_NODES);
    int s = 0;
    for (int i = lo; i < hi; ++i) s += cnt[i];
    part[t] = s;
    __syncthreads();
    for (int off = 1; off < 1024; off <<= 1) {
        int v = (t >= off) ? part[t - off] : 0;
        __syncthreads();
        if (t >= off) part[t] += v;
        __syncthreads();
    }
    int run = (t > 0) ? part[t - 1] : 0;
    for (int i = lo; i < hi; ++i) {
        row_start[i] = run;
        cursor[i] = run;
        run += cnt[i];
    }
    if (t == 1023) row_start[N_NODES] = part[1023];
}

__global__ void scatter_kernel(const int* __restrict__ rows, const int* __restrict__ cols,
                               const float* __restrict__ vals, int* __restrict__ cursor,
                               float2* __restrict__ epack) {
    int e = blockIdx.x * blockDim.x + threadIdx.x;
    if (e >= N_EDGES) return;
    int r = rows[e];
    int p = atomicAdd(&cursor[r], 1);
    epack[p] = make_float2(vals[e], __int_as_float(cols[e]));
}

// ---------------- f(z) = LayerNorm(K*z + A z) [+ fused Anderson reduce] ------
// R3-proven structure: 5000 blocks x 128 threads, half-wave per row, float4
// per lane, shfl-broadcast edges, XCD swizzle (b&7 == graph).
// RED=1 (t=6) / RED=2 (t=7): fused H-reduction. zlast == feval input z (zv in
// reg) and F_t == ov (in reg) in BOTH iterations, so only 4/5 extra float4
// loads per thread; block-level butterfly + 8-replica atomics.

struct Slots5 { const float* s[5]; };

__device__ __forceinline__ float dot4(float4 a, float4 b) {
    return a.x * b.x + a.y * b.y + a.z * b.z + a.w * b.w;
}
__device__ __forceinline__ float4 sub4(float4 a, float4 b) {
    return make_float4(a.x - b.x, a.y - b.y, a.z - b.z, a.w - b.w);
}

template <int RED>
__global__ __launch_bounds__(128) void feval_kernel(const float* __restrict__ z,
                                                    const float* __restrict__ Kd,
                                                    const float* __restrict__ lnw,
                                                    const float* __restrict__ lnb,
                                                    const int* __restrict__ row_start,
                                                    const float2* __restrict__ epack,
                                                    float* __restrict__ out,
                                                    Slots5 sl,
                                                    float* __restrict__ red) {
    int b = blockIdx.x;
    int g = b & 7;                 // XCD id == graph id (round-robin dispatch)
    int j = b >> 3;                // 0..624 within graph
    int wv = threadIdx.x >> 6;     // wave in block: 0..1
    int lane = threadIdx.x & 63;
    int l = lane & 31;             // lane within half-wave
    int r = g * NPG + (j << 2) + (wv << 1) + (lane >> 5);
    int d0 = l << 2;               // dims d0..d0+3

    int e0 = row_start[r], e1 = row_start[r + 1];

    float4 zv = *(const float4*)(z + (size_t)r * DD + d0);
    float kd = Kd[r];
    float a0 = kd * zv.x, a1 = kd * zv.y, a2 = kd * zv.z, a3 = kd * zv.w;

    for (int base = e0; base < e1; base += 32) {
        int ew = base + l;
        float2 my_e = (ew < e1) ? epack[ew] : make_float2(0.0f, 0.0f);
        float my_val = my_e.x;
        int my_col = __float_as_int(my_e.y);
        int m = min(32, e1 - base);
        int i = 0;
        for (; i + 4 <= m; i += 4) {
            int c0 = __shfl(my_col, i, 32);
            int c1 = __shfl(my_col, i + 1, 32);
            int c2 = __shfl(my_col, i + 2, 32);
            int c3 = __shfl(my_col, i + 3, 32);
            float v0 = __shfl(my_val, i, 32);
            float v1 = __shfl(my_val, i + 1, 32);
            float v2 = __shfl(my_val, i + 2, 32);
            float v3 = __shfl(my_val, i + 3, 32);
            float4 z0 = *(const float4*)(z + (size_t)c0 * DD + d0);
            float4 z1 = *(const float4*)(z + (size_t)c1 * DD + d0);
            float4 z2 = *(const float4*)(z + (size_t)c2 * DD + d0);
            float4 z3 = *(const float4*)(z + (size_t)c3 * DD + d0);
            a0 = fmaf(v0, z0.x, a0); a1 = fmaf(v0, z0.y, a1); a2 = fmaf(v0, z0.z, a2); a3 = fmaf(v0, z0.w, a3);
            a0 = fmaf(v1, z1.x, a0); a1 = fmaf(v1, z1.y, a1); a2 = fmaf(v1, z1.z, a2); a3 = fmaf(v1, z1.w, a3);
            a0 = fmaf(v2, z2.x, a0); a1 = fmaf(v2, z2.y, a1); a2 = fmaf(v2, z2.z, a2); a3 = fmaf(v2, z2.w, a3);
            a0 = fmaf(v3, z3.x, a0); a1 = fmaf(v3, z3.y, a1); a2 = fmaf(v3, z3.z, a2); a3 = fmaf(v3, z3.w, a3);
        }
        for (; i < m; ++i) {
            int c = __shfl(my_col, i, 32);
            float v = __shfl(my_val, i, 32);
            float4 zc = *(const float4*)(z + (size_t)c * DD + d0);
            a0 = fmaf(v, zc.x, a0); a1 = fmaf(v, zc.y, a1);
            a2 = fmaf(v, zc.z, a2); a3 = fmaf(v, zc.w, a3);
        }
    }

    // half-wave (32-lane) LayerNorm stats over 128 values (4 per lane)
    float s = a0 + a1 + a2 + a3;
    float sq = a0 * a0 + a1 * a1 + a2 * a2 + a3 * a3;
#pragma unroll
    for (int off = 16; off; off >>= 1) {
        s += __shfl_xor(s, off, 64);   // offsets < 32 keep halves separate
        sq += __shfl_xor(sq, off, 64);
    }
    float mu = s * (1.0f / DD);
    float var = sq * (1.0f / DD) - mu * mu;
    float rstd = rsqrtf(var + 1e-5f);

    float4 wv4 = *(const float4*)(lnw + d0);
    float4 bv4 = *(const float4*)(lnb + d0);
    float4 ov;
    ov.x = wv4.x * (a0 - mu) * rstd + bv4.x;
    ov.y = wv4.y * (a1 - mu) * rstd + bv4.y;
    ov.z = wv4.z * (a2 - mu) * rstd + bv4.z;
    ov.w = wv4.w * (a3 - mu) * rstd + bv4.w;
    *(float4*)(out + (size_t)r * DD + d0) = ov;

    if constexpr (RED > 0) {
        // history slots for this element; p[4] = zv when it aliases the input
        float4 p[5];
#pragma unroll
        for (int c = 0; c < 4; ++c) p[c] = *(const float4*)(sl.s[c] + (size_t)r * DD + d0);
        if constexpr (RED == 2) p[4] = *(const float4*)(sl.s[4] + (size_t)r * DD + d0);
        else                    p[4] = zv;
        float4 G[5];
#pragma unroll
        for (int c = 0; c < 4; ++c) G[c] = sub4(p[c + 1], p[c]);
        G[4] = sub4(ov, zv);               // F_t - z_t, both in registers
        float4 dg[4];
#pragma unroll
        for (int a = 0; a < 4; ++a) dg[a] = sub4(G[a + 1], G[a]);

        float acc[14];
        int k = 0;
#pragma unroll
        for (int a = 0; a < 4; ++a)
#pragma unroll
            for (int bb = a; bb < 4; ++bb) { acc[k] = dot4(dg[a], dg[bb]); ++k; }
#pragma unroll
        for (int a = 0; a < 4; ++a) acc[10 + a] = dot4(dg[a], G[4]);

#pragma unroll
        for (int off = 32; off; off >>= 1)
#pragma unroll
            for (int kk = 0; kk < 14; ++kk) acc[kk] += __shfl_xor(acc[kk], off, 64);

        __shared__ float sh[2][14];
        int wv2 = threadIdx.x >> 6, l64 = threadIdx.x & 63;
        if (l64 == 0)
#pragma unroll
            for (int kk = 0; kk < 14; ++kk) sh[wv2][kk] = acc[kk];
        __syncthreads();
        if (threadIdx.x < 14)
            atomicAdd(&red[(threadIdx.x * 8 + (blockIdx.x & 7)) * 16],
                      sh[0][threadIdx.x] + sh[1][threadIdx.x]);
    }
}

// ---------------- Anderson update (solve fused; replicas summed in parallel) --

struct Cols5 { const float* f[5]; };

// H = dG^T dG + 0.1 I is SPD -> unpivoted elimination, fully unrolled.
__device__ __forceinline__ float solve_gamma_vals(const float* rl, float* g) {
    float A[4][4], b[4];
    int k = 0;
#pragma unroll
    for (int a = 0; a < 4; ++a)
#pragma unroll
        for (int c = a; c < 4; ++c) { float h = rl[k]; A[a][c] = h; A[c][a] = h; ++k; }
#pragma unroll
    for (int a = 0; a < 4; ++a) A[a][a] += 0.1f;
#pragma unroll
    for (int a = 0; a < 4; ++a) b[a] = rl[10 + a];

#pragma unroll
    for (int col = 0; col < 4; ++col) {
        float inv = 1.0f / A[col][col];
#pragma unroll
        for (int rr = 0; rr < 4; ++rr) {
            if (rr > col) {
                float m = A[rr][col] * inv;
#pragma unroll
                for (int c2 = 0; c2 < 4; ++c2)
                    if (c2 >= col) A[rr][c2] -= m * A[col][c2];
                b[rr] -= m * b[col];
            }
        }
    }
#pragma unroll
    for (int rr = 3; rr >= 0; --rr) {
        float s = b[rr];
#pragma unroll
        for (int c2 = 0; c2 < 4; ++c2)
            if (c2 > rr) s -= A[rr][c2] * g[c2];
        g[rr] = s / A[rr][rr];
    }
    bool fin = isfinite(g[0]) && isfinite(g[1]) && isfinite(g[2]) && isfinite(g[3]);
    return fin ? 1.0f : 0.0f;
}

__global__ __launch_bounds__(256) void update_kernel(Cols5 c, const float* __restrict__ red,
                                                     float* __restrict__ zout) {
    __shared__ float srl[14];
    __shared__ float sg[5];
    // 14 threads sum their counter's 8 replicas in parallel (was thread0 serial)
    if (threadIdx.x < 14) {
        float h = 0.f;
#pragma unroll
        for (int rep = 0; rep < 8; ++rep) h += red[(threadIdx.x * 8 + rep) * 16];
        srl[threadIdx.x] = h;
    }
    __syncthreads();
    if (threadIdx.x == 0) {
        float gg[4];
        float flag = solve_gamma_vals(srl, gg);
        sg[0] = gg[0]; sg[1] = gg[1]; sg[2] = gg[2]; sg[3] = gg[3]; sg[4] = flag;
    }
    __syncthreads();
    float g0 = sg[0], g1 = sg[1], g2 = sg[2], g3 = sg[3], flag = sg[4];

    int j = blockIdx.x * blockDim.x + threadIdx.x;
    if (j >= ND4) return;
    float4 f0 = ((const float4*)c.f[0])[j];
    float4 f1 = ((const float4*)c.f[1])[j];
    float4 f2 = ((const float4*)c.f[2])[j];
    float4 f3 = ((const float4*)c.f[3])[j];
    float4 f4 = ((const float4*)c.f[4])[j];
    float4 o;
    if (flag != 0.0f) {
        o.x = f4.x - 0.5f * ((f1.x - f0.x) * g0 + (f2.x - f1.x) * g1 + (f3.x - f2.x) * g2 + (f4.x - f3.x) * g3);
        o.y = f4.y - 0.5f * ((f1.y - f0.y) * g0 + (f2.y - f1.y) * g1 + (f3.y - f2.y) * g2 + (f4.y - f3.y) * g3);
        o.z = f4.z - 0.5f * ((f1.z - f0.z) * g0 + (f2.z - f1.z) * g1 + (f3.z - f2.z) * g2 + (f4.z - f3.z) * g3);
        o.w = f4.w - 0.5f * ((f1.w - f0.w) * g0 + (f2.w - f1.w) * g1 + (f3.w - f2.w) * g2 + (f4.w - f3.w) * g3);
    } else {
        o = f4;
    }
    ((float4*)zout)[j] = o;
}

// ---------------- host ----------------

extern "C" void kernel_launch(void* const* d_in, const int* in_sizes, int n_in,
                              void* d_out, int out_size, void* d_ws, size_t ws_size,
                              hipStream_t stream) {
    const float* x_init = (const float*)d_in[0];
    const float* Kd     = (const float*)d_in[1];
    const float* vals   = (const float*)d_in[2];
    const float* lnw    = (const float*)d_in[3];
    const float* lnb    = (const float*)d_in[4];
    const int*   rows   = (const int*)d_in[5];
    const int*   cols   = (const int*)d_in[6];
    float* out = (float*)d_out;

    char* p = (char*)d_ws;
    auto carve = [&](size_t bytes) -> void* {
        void* r = (void*)p;
        p += (bytes + 255) & ~(size_t)255;
        return r;
    };
    float*  Fh        = (float*)carve((size_t)6 * ND * 4);   // rolling f_t history, slot t%6
    float*  red       = (float*)carve(2 * RED_FLOATS * 4);   // 2 sets x 14 ctrs x 8 replicas
    int*    row_start = (int*)carve((N_NODES + 1) * 4);
    int*    cursor    = (int*)carve(N_NODES * 4);
    int*    cnt       = (int*)carve(N_NODES * 4);
    float2* epack     = (float2*)carve((size_t)N_EDGES * 8);
    float*  zA        = out;  // d_out doubles as storage for Anderson z7

    // CSR build (once per launch); scan also zeros both red sets
    hipMemsetAsync(cnt, 0, N_NODES * 4, stream);
    count_kernel<<<(N_EDGES + 255) / 256, 256, 0, stream>>>(rows, cnt);
    scan_kernel<<<1, 1024, 0, stream>>>(cnt, row_start, cursor, red);
    scatter_kernel<<<(N_EDGES + 255) / 256, 256, 0, stream>>>(rows, cols, vals, cursor, epack);

    auto Fslot = [&](int t) -> float* { return Fh + (size_t)(t % 6) * ND; };

    Slots5 sl0 = {};   // unused for RED=0
    for (int t = 0; t < 8; ++t) {
        const float* zsrc = (t == 0) ? x_init : (t <= 6 ? Fslot(t - 1) : zA);

        if (t < 6) {
            feval_kernel<0><<<5000, 128, 0, stream>>>(zsrc, Kd, lnw, lnb, row_start, epack,
                                                      Fslot(t), sl0, (float*)nullptr);
        } else {
            float* redt = red + (t - 6) * RED_FLOATS;
            Slots5 sl;
            if (t == 6) {
                // s6 = F1..F6; s6[4]=F5=zsrc (in-reg zv), s6[5]=F6 (in-reg ov)
                for (int c = 0; c < 4; ++c) sl.s[c] = Fslot(1 + c);
                sl.s[4] = Fslot(5);   // unused (RED=1 uses zv)
                feval_kernel<1><<<5000, 128, 0, stream>>>(zsrc, Kd, lnw, lnb, row_start, epack,
                                                          Fslot(t), sl, redt);
            } else {
                // s6 = F2..F7; load F2..F6, F7 = ov, zlast = zA = zv
                for (int c = 0; c < 5; ++c) sl.s[c] = Fslot(2 + c);
                feval_kernel<2><<<5000, 128, 0, stream>>>(zsrc, Kd, lnw, lnb, row_start, epack,
                                                          Fslot(t), sl, redt);
            }

            Cols5 uc;
            for (int c2 = 0; c2 < 5; ++c2) uc.f[c2] = Fslot(t - 4 + c2);
            float* zdst = (t == 6) ? zA : out;
            update_kernel<<<(ND4 + 255) / 256, 256, 0, stream>>>(uc, redt, zdst);
        }
    }
}